// Round 3
// baseline (15035.536 us; speedup 1.0000x reference)
//
#include <hip/hip_runtime.h>

typedef unsigned short u16;
typedef __attribute__((ext_vector_type(8))) short bf16x8;
typedef __attribute__((ext_vector_type(4))) float f32x4;

#define B_   128
#define T_   512
#define NOBS 256
#define H_   512
#define G4   2048
#define NACT 32
#define M_   (B_*T_)   // 65536
#define GR   8         // batch islands
#define ROWS 16        // batch rows per WG
#define UN   16        // hidden units per WG

__device__ __forceinline__ float b2f(u16 s) {
  union { unsigned u; float f; } v; v.u = ((unsigned)s) << 16; return v.f;
}
__device__ __forceinline__ u16 f2b(float f) {
  union { float f; unsigned u; } v; v.f = f;
  unsigned r = v.u + 0x7FFFu + ((v.u >> 16) & 1u);
  return (u16)(r >> 16);
}
__device__ __forceinline__ float sigm(float x) { return 1.f/(1.f+__expf(-x)); }
__device__ __forceinline__ float tanh_f(float x) { return 1.f - 2.f/(1.f+__expf(2.f*x)); }

// global -> LDS direct copy, 16B per lane. ldsbase wave-uniform; HW adds lane*16.
__device__ __forceinline__ void gld16(const void* g, void* ldsbase) {
#if __has_builtin(__builtin_amdgcn_global_load_lds)
  __builtin_amdgcn_global_load_lds((const __attribute__((address_space(1))) void*)g,
                                   (__attribute__((address_space(3))) void*)ldsbase, 16, 0, 0);
#else
  ((float4*)ldsbase)[threadIdx.x & 63] = *(const float4*)g;
#endif
}

// ---------------- prep kernels ----------------
__global__ void k_cvt(const float* __restrict__ in, u16* __restrict__ out, int n4) {
  int stride = gridDim.x * blockDim.x;
  for (int i = blockIdx.x*blockDim.x + threadIdx.x; i < n4; i += stride) {
    float4 v = ((const float4*)in)[i];
    uint2 p;
    p.x = (unsigned)f2b(v.x) | ((unsigned)f2b(v.y) << 16);
    p.y = (unsigned)f2b(v.z) | ((unsigned)f2b(v.w) << 16);
    ((uint2*)out)[i] = p;
  }
}

// obs (B,T,NOBS) f32 -> obsT (T,B,NOBS) bf16 ; one 8-elem chunk per thread
__global__ void k_cvt_obsT(const float* __restrict__ in, u16* __restrict__ out) {
  const long i = (long)blockIdx.x*blockDim.x + threadIdx.x;   // chunk id, 8 elems
  const int k8 = (int)(i & (NOBS/8 - 1));
  const long row = i >> 5;                 // t*B + b
  const int t = (int)(row >> 7), b = (int)(row & (B_-1));
  const float* src = in + ((long)b*T_ + t)*NOBS + k8*8;
  ushort2 o[4];
  #pragma unroll
  for (int q = 0; q < 4; ++q) {
    o[q].x = f2b(src[q*2]);
    o[q].y = f2b(src[q*2+1]);
  }
  *(ushort2*)&out[i*8+0] = o[0]; *(ushort2*)&out[i*8+2] = o[1];
  *(ushort2*)&out[i*8+4] = o[2]; *(ushort2*)&out[i*8+6] = o[3];
}

// out (C,R) bf16 <- in (R,C) f32 :  out[c*R+r] = in[r*C+c]
__global__ void k_transpose(const float* __restrict__ in, u16* __restrict__ out, int R, int C) {
  int i = blockIdx.x*blockDim.x + threadIdx.x;
  if (i < R*C) {
    int c = i / R, r = i - c*R;
    out[i] = f2b(in[r*C + c]);
  }
}

// ---------------- GEMM: C(M,N) = A(M,K) @ BT(N,K)^T, bf16 in/out, f32 accum ----------------
template<int EPI>
__global__ __launch_bounds__(256) void k_gemm_bt(const u16* __restrict__ A, const u16* __restrict__ BT,
                                                 u16* __restrict__ C, const float* __restrict__ bias,
                                                 int M, int N, int K)
{
  __shared__ u16 As[128*64];
  __shared__ u16 Bs[128*64];
  const int tid = threadIdx.x, wv = tid >> 6, lane = tid & 63;
  const int ntile = N >> 7;
  const int tm = blockIdx.x / ntile, tn = blockIdx.x - tm*ntile;
  const int wr = wv >> 1, wc = wv & 1;
  f32x4 acc[4][4];
  for (int m=0;m<4;++m) for (int n=0;n<4;++n) acc[m][n] = (f32x4){0.f,0.f,0.f,0.f};
  const long abase = (long)tm*128, bbase = (long)tn*128;
  const int kit = K >> 6;
  for (int kt = 0; kt < kit; ++kt) {
    const int k0 = kt << 6;
    #pragma unroll
    for (int q = 0; q < 4; ++q) {
      int off = (wv*4+q)*1024 + lane*16;
      int row = off >> 7, colb = off & 127;
      gld16((const char*)A  + ((abase+row)*K + k0)*2 + colb, (char*)As + (wv*4+q)*1024);
      gld16((const char*)BT + ((bbase+row)*K + k0)*2 + colb, (char*)Bs + (wv*4+q)*1024);
    }
    asm volatile("s_waitcnt vmcnt(0)" ::: "memory");
    __syncthreads();
    const int kg = (lane >> 4) * 8;
    #pragma unroll
    for (int kk = 0; kk < 64; kk += 32) {
      bf16x8 af[4], bfr[4];
      #pragma unroll
      for (int m = 0; m < 4; ++m)
        af[m] = *(const bf16x8*)(As + (wr*64 + m*16 + (lane&15))*64 + kk + kg);
      #pragma unroll
      for (int n = 0; n < 4; ++n)
        bfr[n] = *(const bf16x8*)(Bs + (wc*64 + n*16 + (lane&15))*64 + kk + kg);
      #pragma unroll
      for (int m = 0; m < 4; ++m)
        #pragma unroll
        for (int n = 0; n < 4; ++n)
          acc[m][n] = __builtin_amdgcn_mfma_f32_16x16x32_bf16(af[m], bfr[n], acc[m][n], 0, 0, 0);
    }
    __syncthreads();
  }
  const int rq = (lane >> 4) * 4, cl = lane & 15;
  #pragma unroll
  for (int n = 0; n < 4; ++n) {
    const int coln = (int)bbase + wc*64 + n*16 + cl;
    const float bv = (EPI == 1) ? bias[coln] : 0.f;
    #pragma unroll
    for (int m = 0; m < 4; ++m) {
      const long rowb = abase + wr*64 + m*16 + rq;
      #pragma unroll
      for (int q = 0; q < 4; ++q) {
        float v = acc[m][n][q];
        if (EPI == 1) v = fmaxf(v + bv, 0.f);
        C[(rowb+q)*(long)N + coln] = f2b(v);
      }
    }
  }
}

// ---------------- persistent LSTM scan ----------------
// grid 256 = 8 islands (16 batch rows) x 32 unit-slices (16 hidden units).
// Weight slice (Wx,Wh cols for my 64 gate-cols) lives in LDS all 512 steps.
// Island-local barrier per step: atomicAdd(RELEASE,AGENT) + acquire spin.
__global__ __launch_bounds__(256, 1) void k_scan(
    const u16* __restrict__ obsT, const u16* __restrict__ WxT, const u16* __restrict__ WhT,
    const float* __restrict__ bvec, const float* __restrict__ c0f,
    u16* __restrict__ hbuf0, u16* __restrict__ hbuf1,
    u16* __restrict__ ys, float* __restrict__ outh, float* __restrict__ outc,
    int* __restrict__ cnt)
{
  __shared__ u16 Bw[96*64*8];        // [kg 0..95][col 0..63][8]  (96 KB)
  __shared__ float zs[2][16*64];     // split-K partials (8 KB)
  __shared__ float cst[ROWS*UN];     // cell state slice (1 KB)
  __shared__ float bsl[64];          // bias slice

  const int tid = threadIdx.x, wv = tid >> 6, lane = tid & 63;
  const int wg = blockIdx.x, r = wg & (GR-1), cg = wg >> 3;
  const int rb0 = r*ROWS, S0 = cg*UN;

  // one-time: weight slice into LDS. kg<32 -> Wx (k=kg*8); else Wh (k=(kg-32)*8)
  for (int idx = tid; idx < 96*64; idx += 256) {
    const int kg = idx >> 6, col = idx & 63;
    const long jrow = (long)((col >> 4)*H_ + S0 + (col & 15));
    const u16* src = (kg < 32) ? (WxT + jrow*NOBS + kg*8)
                               : (WhT + jrow*H_ + (long)(kg-32)*8);
    *(bf16x8*)(Bw + (long)idx*8) = *(const bf16x8*)src;
  }
  {
    const int rr = tid >> 4, sl = tid & 15;
    cst[tid] = c0f[(rb0 + rr)*H_ + S0 + sl];
    if (tid < 64) bsl[tid] = bvec[(tid >> 4)*H_ + S0 + (tid & 15)];
  }
  __syncthreads();

  const int kh = wv >> 1, ch = wv & 1;     // wave = (k-half, col-half)
  const int C0 = ch*32;
  const int lq = lane >> 4, l15 = lane & 15;
  const int arow = rb0 + l15;
  const int ldsC = (C0 + l15)*8;           // + kg*512 elems

  for (int t = 0; t < T_; ++t) {
    const u16* hc = (t & 1) ? hbuf1 : hbuf0;
    u16* hw = (t & 1) ? hbuf0 : hbuf1;

    f32x4 acc0 = {0.f,0.f,0.f,0.f}, acc1 = {0.f,0.f,0.f,0.f};
    // phase 1: obs_t @ Wx   (my k-half: 4 of 8 k-slices)
    {
      const u16* Ax = obsT + ((long)t*B_ + arow)*NOBS + kh*128 + lq*8;
      #pragma unroll
      for (int ks = 0; ks < 4; ++ks) {
        bf16x8 a  = *(const bf16x8*)(Ax + ks*32);
        const u16* bp = Bw + (kh*16 + ks*4 + lq)*512 + ldsC;
        bf16x8 b0 = *(const bf16x8*)bp;
        bf16x8 b1 = *(const bf16x8*)(bp + 128);
        acc0 = __builtin_amdgcn_mfma_f32_16x16x32_bf16(a, b0, acc0, 0, 0, 0);
        acc1 = __builtin_amdgcn_mfma_f32_16x16x32_bf16(a, b1, acc1, 0, 0, 0);
      }
    }
    // phase 2: h @ Wh   (my k-half: 8 of 16 k-slices)
    {
      const u16* Ah = hc + (long)arow*H_ + kh*256 + lq*8;
      #pragma unroll
      for (int ks = 0; ks < 8; ++ks) {
        bf16x8 a  = *(const bf16x8*)(Ah + ks*32);
        const u16* bp = Bw + (32 + kh*32 + ks*4 + lq)*512 + ldsC;
        bf16x8 b0 = *(const bf16x8*)bp;
        bf16x8 b1 = *(const bf16x8*)(bp + 128);
        acc0 = __builtin_amdgcn_mfma_f32_16x16x32_bf16(a, b0, acc0, 0, 0, 0);
        acc1 = __builtin_amdgcn_mfma_f32_16x16x32_bf16(a, b1, acc1, 0, 0, 0);
      }
    }
    {
      const int zr0 = lq*4, zc = C0 + l15;   // D: col=lane&15, row=(lane>>4)*4+q
      #pragma unroll
      for (int q = 0; q < 4; ++q) {
        zs[kh][(zr0+q)*64 + zc]      = acc0[q];
        zs[kh][(zr0+q)*64 + zc + 16] = acc1[q];
      }
    }
    __syncthreads();

    // epilogue: one (row, unit) per thread
    {
      const int rr = tid >> 4, sl = tid & 15;
      const float* z0 = &zs[0][rr*64];
      const float* z1 = &zs[1][rr*64];
      const float zi = z0[sl]      + z1[sl]      + bsl[sl];
      const float zf = z0[16+sl]   + z1[16+sl]   + bsl[16+sl];
      const float zg = z0[32+sl]   + z1[32+sl]   + bsl[32+sl];
      const float zo = z0[48+sl]   + z1[48+sl]   + bsl[48+sl];
      const float cv = cst[tid];
      const float cn = sigm(zf)*cv + sigm(zi)*tanh_f(zg);
      const float hv = sigm(zo)*tanh_f(cn);
      cst[tid] = cn;
      const int b = rb0 + rr;
      const u16 hb = f2b(hv);
      hw[(long)b*H_ + S0 + sl] = hb;
      ys[((long)b*T_ + t)*H_ + S0 + sl] = hb;
      if (t == T_-1) { outh[b*H_ + S0 + sl] = hv; outc[b*H_ + S0 + sl] = cn; }
    }

    if (t < T_-1) {
      __threadfence();            // release my h stores (agent scope)
      __syncthreads();            // all threads' stores+fences done
      if (tid == 0) {
        int* c = cnt + (t*GR + r);
        __hip_atomic_fetch_add(c, 1, __ATOMIC_RELEASE, __HIP_MEMORY_SCOPE_AGENT);
        while (__hip_atomic_load(c, __ATOMIC_ACQUIRE, __HIP_MEMORY_SCOPE_AGENT) < 32)
          __builtin_amdgcn_s_sleep(1);
      }
      __syncthreads();            // releases WG; also fences zs for next iter
    }
  }
}

// ---------------- head ----------------
__global__ __launch_bounds__(256) void k_head(const u16* __restrict__ X, const u16* __restrict__ WoT,
    const float* __restrict__ bo, const float* __restrict__ amin, const float* __restrict__ amax,
    float* __restrict__ out)
{
  __shared__ u16 Ws[NACT*H_];
  __shared__ float sc[3*NACT];
  const int tid = threadIdx.x;
  #pragma unroll
  for (int q = 0; q < 8; ++q)
    ((float4*)Ws)[q*256 + tid] = ((const float4*)WoT)[q*256 + tid];
  if (tid < NACT) { sc[tid] = bo[tid]; sc[NACT+tid] = amin[tid]; sc[2*NACT+tid] = amax[tid]; }
  __syncthreads();
  const long r = (long)blockIdx.x*64 + (tid >> 2);
  const int c0 = (tid & 3)*8;
  float acc[8];
  #pragma unroll
  for (int c = 0; c < 8; ++c) acc[c] = 0.f;
  const u16* Arow = X + r*H_;
  for (int kc = 0; kc < H_/8; ++kc) {
    bf16x8 a = *(const bf16x8*)(Arow + kc*8);
    float av[8];
    #pragma unroll
    for (int j = 0; j < 8; ++j) av[j] = b2f((u16)a[j]);
    #pragma unroll
    for (int c = 0; c < 8; ++c) {
      bf16x8 w = *(const bf16x8*)(Ws + (c0+c)*H_ + kc*8);
      #pragma unroll
      for (int j = 0; j < 8; ++j) acc[c] += av[j] * b2f((u16)w[j]);
    }
  }
  #pragma unroll
  for (int c = 0; c < 8; ++c) {
    const int cc = c0 + c;
    const float y = acc[c] + sc[cc];
    const float tv = tanhf(y);
    out[r*NACT + cc] = 0.5f*(tv*(sc[2*NACT+cc]-sc[NACT+cc]) + (sc[2*NACT+cc]+sc[NACT+cc]));
  }
}

extern "C" void kernel_launch(void* const* d_in, const int* in_sizes, int n_in,
                              void* d_out, int out_size, void* d_ws, size_t ws_size,
                              hipStream_t stream) {
  const float* obs = (const float*)d_in[0];
  const float* h0  = (const float*)d_in[1];
  const float* c0  = (const float*)d_in[2];
  const float* Wx  = (const float*)d_in[3];
  const float* Wh  = (const float*)d_in[4];
  const float* bb  = (const float*)d_in[5];
  const float* W1  = (const float*)d_in[6];
  const float* b1  = (const float*)d_in[7];
  const float* W2  = (const float*)d_in[8];
  const float* b2  = (const float*)d_in[9];
  const float* Wo  = (const float*)d_in[10];
  const float* bo  = (const float*)d_in[11];
  const float* amin= (const float*)d_in[12];
  const float* amax= (const float*)d_in[13];

  char* ws = (char*)d_ws;
  // workspace layout (bytes), end ~172.3 MiB (<= round-2's verified footprint):
  u16* obsT  = (u16*)(ws + 0);                 // (T,B,NOBS) bf16, 32 MiB
  u16* ys    = (u16*)(ws + 33554432);          // (B,T,H) bf16, 64 MiB
  u16* t1    = (u16*)(ws + 100663296);         // 64 MiB
  u16* t2    = (u16*)(ws + 33554432);          // alias ys (dead after W1-GEMM)
  u16* WxT   = (u16*)(ws + 167772160);         // (G4, NOBS)  1 MiB
  u16* WhT   = (u16*)(ws + 168820736);         // (G4, H)     2 MiB
  u16* W1T   = (u16*)(ws + 170917888);         // 0.5 MiB
  u16* W2T   = (u16*)(ws + 171442176);         // 0.5 MiB
  u16* WoT   = (u16*)(ws + 171966464);         // 64 KiB
  u16* hb0   = (u16*)(ws + 171999232);         // 128 KiB
  u16* hb1   = (u16*)(ws + 172130304);         // 128 KiB
  int* cnt   = (int*)(ws + 172261376);         // 512*8*4 = 16 KiB

  float* outA = (float*)d_out;
  float* outh = outA + (long)M_*NACT;
  float* outc = outh + B_*H_;

  hipMemsetAsync(cnt, 0, T_*GR*sizeof(int), stream);
  k_cvt_obsT<<<M_*NOBS/8/256, 256, 0, stream>>>(obs, obsT);
  k_cvt<<<64, 256, 0, stream>>>(h0, hb0, B_*H_/4);
  k_transpose<<<2048, 256, 0, stream>>>(Wx, WxT, NOBS, G4);
  k_transpose<<<4096, 256, 0, stream>>>(Wh, WhT, H_, G4);
  k_transpose<<<1024, 256, 0, stream>>>(W1, W1T, H_, H_);
  k_transpose<<<1024, 256, 0, stream>>>(W2, W2T, H_, H_);
  k_transpose<<<64,   256, 0, stream>>>(Wo, WoT, H_, NACT);

  // persistent scan: 256 co-resident WGs (1/CU), island-local barriers
  k_scan<<<256, 256, 0, stream>>>(obsT, WxT, WhT, bb, c0, hb0, hb1, ys, outh, outc, cnt);

  // MLP head
  k_gemm_bt<1><<<(M_/128)*(H_/128), 256, 0, stream>>>(ys, W1T, t1, b1, M_, H_, H_);
  k_gemm_bt<1><<<(M_/128)*(H_/128), 256, 0, stream>>>(t1, W2T, t2, b2, M_, H_, H_);
  k_head<<<M_/64, 256, 0, stream>>>(t2, WoT, bo, amin, amax, outA);
}

// Round 4
// 2395.524 us; speedup vs baseline: 6.2765x; 6.2765x over previous
//
#include <hip/hip_runtime.h>

typedef unsigned short u16;
typedef unsigned long long ull;
typedef __attribute__((ext_vector_type(8))) short bf16x8;
typedef __attribute__((ext_vector_type(4))) float f32x4;

#define B_   128
#define T_   512
#define NOBS 256
#define H_   512
#define G4   2048
#define NACT 32
#define M_   (B_*T_)   // 65536
#define GR   8         // batch islands
#define ROWS 16        // batch rows per WG
#define UN   16        // hidden units per WG

__device__ __forceinline__ float b2f(u16 s) {
  union { unsigned u; float f; } v; v.u = ((unsigned)s) << 16; return v.f;
}
__device__ __forceinline__ u16 f2b(float f) {
  union { float f; unsigned u; } v; v.f = f;
  unsigned r = v.u + 0x7FFFu + ((v.u >> 16) & 1u);
  return (u16)(r >> 16);
}
__device__ __forceinline__ float sigm(float x) { return 1.f/(1.f+__expf(-x)); }
__device__ __forceinline__ float tanh_f(float x) { return 1.f - 2.f/(1.f+__expf(2.f*x)); }

// global -> LDS direct copy, 16B per lane. ldsbase wave-uniform; HW adds lane*16.
__device__ __forceinline__ void gld16(const void* g, void* ldsbase) {
#if __has_builtin(__builtin_amdgcn_global_load_lds)
  __builtin_amdgcn_global_load_lds((const __attribute__((address_space(1))) void*)g,
                                   (__attribute__((address_space(3))) void*)ldsbase, 16, 0, 0);
#else
  ((float4*)ldsbase)[threadIdx.x & 63] = *(const float4*)g;
#endif
}

// ---------------- prep kernels ----------------
__global__ void k_cvt(const float* __restrict__ in, u16* __restrict__ out, int n4) {
  int stride = gridDim.x * blockDim.x;
  for (int i = blockIdx.x*blockDim.x + threadIdx.x; i < n4; i += stride) {
    float4 v = ((const float4*)in)[i];
    uint2 p;
    p.x = (unsigned)f2b(v.x) | ((unsigned)f2b(v.y) << 16);
    p.y = (unsigned)f2b(v.z) | ((unsigned)f2b(v.w) << 16);
    ((uint2*)out)[i] = p;
  }
}

// obs (B,T,NOBS) f32 -> obsT (T,B,NOBS) bf16 ; one 8-elem chunk per thread
__global__ void k_cvt_obsT(const float* __restrict__ in, u16* __restrict__ out) {
  const long i = (long)blockIdx.x*blockDim.x + threadIdx.x;   // chunk id, 8 elems
  const int k8 = (int)(i & (NOBS/8 - 1));
  const long row = i >> 5;                 // t*B + b
  const int t = (int)(row >> 7), b = (int)(row & (B_-1));
  const float* src = in + ((long)b*T_ + t)*NOBS + k8*8;
  ushort2 o[4];
  #pragma unroll
  for (int q = 0; q < 4; ++q) {
    o[q].x = f2b(src[q*2]);
    o[q].y = f2b(src[q*2+1]);
  }
  *(ushort2*)&out[i*8+0] = o[0]; *(ushort2*)&out[i*8+2] = o[1];
  *(ushort2*)&out[i*8+4] = o[2]; *(ushort2*)&out[i*8+6] = o[3];
}

// out (C,R) bf16 <- in (R,C) f32 :  out[c*R+r] = in[r*C+c]
__global__ void k_transpose(const float* __restrict__ in, u16* __restrict__ out, int R, int C) {
  int i = blockIdx.x*blockDim.x + threadIdx.x;
  if (i < R*C) {
    int c = i / R, r = i - c*R;
    out[i] = f2b(in[r*C + c]);
  }
}

// ---------------- GEMM: C(M,N) = A(M,K) @ BT(N,K)^T, bf16 in/out, f32 accum ----------------
template<int EPI>
__global__ __launch_bounds__(256) void k_gemm_bt(const u16* __restrict__ A, const u16* __restrict__ BT,
                                                 u16* __restrict__ C, const float* __restrict__ bias,
                                                 int M, int N, int K)
{
  __shared__ u16 As[128*64];
  __shared__ u16 Bs[128*64];
  const int tid = threadIdx.x, wv = tid >> 6, lane = tid & 63;
  const int ntile = N >> 7;
  const int tm = blockIdx.x / ntile, tn = blockIdx.x - tm*ntile;
  const int wr = wv >> 1, wc = wv & 1;
  f32x4 acc[4][4];
  for (int m=0;m<4;++m) for (int n=0;n<4;++n) acc[m][n] = (f32x4){0.f,0.f,0.f,0.f};
  const long abase = (long)tm*128, bbase = (long)tn*128;
  const int kit = K >> 6;
  for (int kt = 0; kt < kit; ++kt) {
    const int k0 = kt << 6;
    #pragma unroll
    for (int q = 0; q < 4; ++q) {
      int off = (wv*4+q)*1024 + lane*16;
      int row = off >> 7, colb = off & 127;
      gld16((const char*)A  + ((abase+row)*K + k0)*2 + colb, (char*)As + (wv*4+q)*1024);
      gld16((const char*)BT + ((bbase+row)*K + k0)*2 + colb, (char*)Bs + (wv*4+q)*1024);
    }
    asm volatile("s_waitcnt vmcnt(0)" ::: "memory");
    __syncthreads();
    const int kg = (lane >> 4) * 8;
    #pragma unroll
    for (int kk = 0; kk < 64; kk += 32) {
      bf16x8 af[4], bfr[4];
      #pragma unroll
      for (int m = 0; m < 4; ++m)
        af[m] = *(const bf16x8*)(As + (wr*64 + m*16 + (lane&15))*64 + kk + kg);
      #pragma unroll
      for (int n = 0; n < 4; ++n)
        bfr[n] = *(const bf16x8*)(Bs + (wc*64 + n*16 + (lane&15))*64 + kk + kg);
      #pragma unroll
      for (int m = 0; m < 4; ++m)
        #pragma unroll
        for (int n = 0; n < 4; ++n)
          acc[m][n] = __builtin_amdgcn_mfma_f32_16x16x32_bf16(af[m], bfr[n], acc[m][n], 0, 0, 0);
    }
    __syncthreads();
  }
  const int rq = (lane >> 4) * 4, cl = lane & 15;
  #pragma unroll
  for (int n = 0; n < 4; ++n) {
    const int coln = (int)bbase + wc*64 + n*16 + cl;
    const float bv = (EPI == 1) ? bias[coln] : 0.f;
    #pragma unroll
    for (int m = 0; m < 4; ++m) {
      const long rowb = abase + wr*64 + m*16 + rq;
      #pragma unroll
      for (int q = 0; q < 4; ++q) {
        float v = acc[m][n][q];
        if (EPI == 1) v = fmaxf(v + bv, 0.f);
        C[(rowb+q)*(long)N + coln] = f2b(v);
      }
    }
  }
}

// ---------------- persistent LSTM scan, v2 ----------------
// grid 256 = 8 islands (16 batch rows) x 32 unit-slices (16 hidden units).
// Per-wave B-fragments (Wx+Wh cols) live in VGPRs for all 512 steps.
// Cross-WG h exchange: relaxed AGENT-scope 8B atomic stores/loads (cache-bypass,
// NO fences -> no buffer_wbl2/buffer_inv). Island barrier = relaxed atomicAdd +
// relaxed spin; ordering via pre-barrier vmcnt drains + in-order wave issue.
__global__ __launch_bounds__(256, 1) void k_scan(
    const u16* __restrict__ obsT, const u16* __restrict__ WxT, const u16* __restrict__ WhT,
    const float* __restrict__ bvec, const float* __restrict__ c0f,
    u16* __restrict__ hbuf0, u16* __restrict__ hbuf1,
    u16* __restrict__ ys, float* __restrict__ outh, float* __restrict__ outc,
    int* __restrict__ cnt)
{
  __shared__ float zs[2][16*64];   // split-K partials
  __shared__ float cst[256];       // cell state slice
  __shared__ float bsl[64];        // bias slice
  __shared__ u16  hsl[256];        // h bf16 staging for packed publish
  __shared__ char pad_[98304];     // occupancy clamp: exactly 1 WG/CU

  const int tid = threadIdx.x, wv = tid >> 6, lane = tid & 63;
  const int wg = blockIdx.x, isl = wg & (GR-1), cg = wg >> 3;
  const int rb0 = isl*ROWS, S0 = cg*UN;

  ((volatile char*)pad_)[tid] = 0;   // keep pad allocated

  const int kh = wv >> 1, ch = wv & 1;     // wave = (k-half, col-half)
  const int C0 = ch*32;
  const int lq = lane >> 4, l15 = lane & 15;
  const int arow = rb0 + l15;

  // ---- load my 24 B-fragments into registers (held for all T steps) ----
  const int j0 = C0 + l15, j1 = j0 + 16;
  const long w0 = (long)((j0 >> 4)*H_ + S0 + (j0 & 15));   // global gate-col rows in WT
  const long w1 = (long)((j1 >> 4)*H_ + S0 + (j1 & 15));
  bf16x8 wbx[4][2], wbh[8][2];
  #pragma unroll
  for (int ks = 0; ks < 4; ++ks) {
    const long k = (long)kh*128 + ks*32 + lq*8;
    wbx[ks][0] = *(const bf16x8*)(WxT + w0*NOBS + k);
    wbx[ks][1] = *(const bf16x8*)(WxT + w1*NOBS + k);
  }
  #pragma unroll
  for (int ks = 0; ks < 8; ++ks) {
    const long k = (long)kh*256 + ks*32 + lq*8;
    wbh[ks][0] = *(const bf16x8*)(WhT + w0*H_ + k);
    wbh[ks][1] = *(const bf16x8*)(WhT + w1*H_ + k);
  }

  cst[tid] = c0f[(rb0 + (tid >> 4))*H_ + S0 + (tid & 15)];
  if (tid < 64) bsl[tid] = bvec[(tid >> 4)*H_ + S0 + (tid & 15)];
  __syncthreads();

  for (int t = 0; t < T_; ++t) {
    const u16* hc = (t & 1) ? hbuf1 : hbuf0;
    u16* hw = (t & 1) ? hbuf0 : hbuf1;

    f32x4 acc0 = {0.f,0.f,0.f,0.f}, acc1 = {0.f,0.f,0.f,0.f};

    // phase X: obs_t @ Wx — h-independent, overlaps barrier wait below
    {
      const u16* Ax = obsT + ((long)t*B_ + arow)*NOBS + kh*128 + lq*8;
      bf16x8 ax[4];
      #pragma unroll
      for (int ks = 0; ks < 4; ++ks) ax[ks] = *(const bf16x8*)(Ax + ks*32);
      #pragma unroll
      for (int ks = 0; ks < 4; ++ks) {
        acc0 = __builtin_amdgcn_mfma_f32_16x16x32_bf16(ax[ks], wbx[ks][0], acc0, 0, 0, 0);
        acc1 = __builtin_amdgcn_mfma_f32_16x16x32_bf16(ax[ks], wbx[ks][1], acc1, 0, 0, 0);
      }
    }

    // island barrier: wait until all 32 WGs published h(t)
    if (t > 0) {
      if (tid == 0) {
        const int* c = cnt + (t-1)*GR + isl;
        while (__hip_atomic_load(c, __ATOMIC_RELAXED, __HIP_MEMORY_SCOPE_AGENT) < 32)
          __builtin_amdgcn_s_sleep(1);
      }
      __syncthreads();
    }

    // phase H: h @ Wh — h via coherent (cache-bypass) relaxed 8B loads
    {
      const u16* Ah = hc + (long)arow*H_ + kh*256 + lq*8;
      ull hq[16];
      #pragma unroll
      for (int ks = 0; ks < 8; ++ks) {
        hq[2*ks]   = __hip_atomic_load((const ull*)(Ah + ks*32),     __ATOMIC_RELAXED, __HIP_MEMORY_SCOPE_AGENT);
        hq[2*ks+1] = __hip_atomic_load((const ull*)(Ah + ks*32 + 4), __ATOMIC_RELAXED, __HIP_MEMORY_SCOPE_AGENT);
      }
      #pragma unroll
      for (int ks = 0; ks < 8; ++ks) {
        union { ull q[2]; bf16x8 v; } ua;
        ua.q[0] = hq[2*ks]; ua.q[1] = hq[2*ks+1];
        acc0 = __builtin_amdgcn_mfma_f32_16x16x32_bf16(ua.v, wbh[ks][0], acc0, 0, 0, 0);
        acc1 = __builtin_amdgcn_mfma_f32_16x16x32_bf16(ua.v, wbh[ks][1], acc1, 0, 0, 0);
      }
    }

    // split-K partials to LDS  (D layout: col=lane&15, row=(lane>>4)*4+q)
    {
      const int zr0 = lq*4, zc = C0 + l15;
      #pragma unroll
      for (int q = 0; q < 4; ++q) {
        zs[kh][(zr0+q)*64 + zc]      = acc0[q];
        zs[kh][(zr0+q)*64 + zc + 16] = acc1[q];
      }
    }
    __syncthreads();

    // epilogue: one (row, unit) per thread
    {
      const int rr = tid >> 4, sl = tid & 15;
      const float* z0 = &zs[0][rr*64];
      const float* z1 = &zs[1][rr*64];
      const float zi = z0[sl]    + z1[sl]    + bsl[sl];
      const float zf = z0[16+sl] + z1[16+sl] + bsl[16+sl];
      const float zg = z0[32+sl] + z1[32+sl] + bsl[32+sl];
      const float zo = z0[48+sl] + z1[48+sl] + bsl[48+sl];
      const float cv = cst[tid];
      const float cn = sigm(zf)*cv + sigm(zi)*tanh_f(zg);
      const float hv = sigm(zo)*tanh_f(cn);
      cst[tid] = cn;
      hsl[tid] = f2b(hv);
      if (t == T_-1) {
        const int b = rb0 + rr;
        outh[b*H_ + S0 + sl] = hv;
        outc[b*H_ + S0 + sl] = cn;
      }
    }
    __syncthreads();

    // wave 0: pack 8B, publish h (coherent store) + ys (plain), then signal.
    // In-wave vmcnt(0) guarantees stores visible before the counter bump.
    if (tid < 64) {
      const int rr = tid >> 2, u4 = (tid & 3)*4;
      const ull pack = *(const ull*)&hsl[rr*16 + u4];
      const int b = rb0 + rr;
      *(ull*)(ys + ((long)b*T_ + t)*H_ + S0 + u4) = pack;
      __hip_atomic_store((ull*)(hw + (long)b*H_ + S0 + u4), pack, __ATOMIC_RELAXED, __HIP_MEMORY_SCOPE_AGENT);
      asm volatile("s_waitcnt vmcnt(0)" ::: "memory");
      if (tid == 0 && t < T_-1)
        __hip_atomic_fetch_add(cnt + t*GR + isl, 1, __ATOMIC_RELAXED, __HIP_MEMORY_SCOPE_AGENT);
    }
    // no trailing barrier needed: next step's zs-__syncthreads orders hsl reuse
  }
}

// ---------------- head ----------------
__global__ __launch_bounds__(256) void k_head(const u16* __restrict__ X, const u16* __restrict__ WoT,
    const float* __restrict__ bo, const float* __restrict__ amin, const float* __restrict__ amax,
    float* __restrict__ out)
{
  __shared__ u16 Ws[NACT*H_];
  __shared__ float sc[3*NACT];
  const int tid = threadIdx.x;
  #pragma unroll
  for (int q = 0; q < 8; ++q)
    ((float4*)Ws)[q*256 + tid] = ((const float4*)WoT)[q*256 + tid];
  if (tid < NACT) { sc[tid] = bo[tid]; sc[NACT+tid] = amin[tid]; sc[2*NACT+tid] = amax[tid]; }
  __syncthreads();
  const long r = (long)blockIdx.x*64 + (tid >> 2);
  const int c0 = (tid & 3)*8;
  float acc[8];
  #pragma unroll
  for (int c = 0; c < 8; ++c) acc[c] = 0.f;
  const u16* Arow = X + r*H_;
  for (int kc = 0; kc < H_/8; ++kc) {
    bf16x8 a = *(const bf16x8*)(Arow + kc*8);
    float av[8];
    #pragma unroll
    for (int j = 0; j < 8; ++j) av[j] = b2f((u16)a[j]);
    #pragma unroll
    for (int c = 0; c < 8; ++c) {
      bf16x8 w = *(const bf16x8*)(Ws + (c0+c)*H_ + kc*8);
      #pragma unroll
      for (int j = 0; j < 8; ++j) acc[c] += av[j] * b2f((u16)w[j]);
    }
  }
  #pragma unroll
  for (int c = 0; c < 8; ++c) {
    const int cc = c0 + c;
    const float y = acc[c] + sc[cc];
    const float tv = tanhf(y);
    out[r*NACT + cc] = 0.5f*(tv*(sc[2*NACT+cc]-sc[NACT+cc]) + (sc[2*NACT+cc]+sc[NACT+cc]));
  }
}

extern "C" void kernel_launch(void* const* d_in, const int* in_sizes, int n_in,
                              void* d_out, int out_size, void* d_ws, size_t ws_size,
                              hipStream_t stream) {
  const float* obs = (const float*)d_in[0];
  const float* h0  = (const float*)d_in[1];
  const float* c0  = (const float*)d_in[2];
  const float* Wx  = (const float*)d_in[3];
  const float* Wh  = (const float*)d_in[4];
  const float* bb  = (const float*)d_in[5];
  const float* W1  = (const float*)d_in[6];
  const float* b1  = (const float*)d_in[7];
  const float* W2  = (const float*)d_in[8];
  const float* b2  = (const float*)d_in[9];
  const float* Wo  = (const float*)d_in[10];
  const float* bo  = (const float*)d_in[11];
  const float* amin= (const float*)d_in[12];
  const float* amax= (const float*)d_in[13];

  char* ws = (char*)d_ws;
  // workspace layout (bytes), end ~164.6 MiB (same proven footprint as round 2/3):
  u16* obsT  = (u16*)(ws + 0);                 // (T,B,NOBS) bf16, 32 MiB
  u16* ys    = (u16*)(ws + 33554432);          // (B,T,H) bf16, 64 MiB
  u16* t1    = (u16*)(ws + 100663296);         // 64 MiB
  u16* t2    = (u16*)(ws + 33554432);          // alias ys (dead after W1-GEMM)
  u16* WxT   = (u16*)(ws + 167772160);         // (G4, NOBS)  1 MiB
  u16* WhT   = (u16*)(ws + 168820736);         // (G4, H)     2 MiB
  u16* W1T   = (u16*)(ws + 170917888);         // 0.5 MiB
  u16* W2T   = (u16*)(ws + 171442176);         // 0.5 MiB
  u16* WoT   = (u16*)(ws + 171966464);         // 64 KiB
  u16* hb0   = (u16*)(ws + 171999232);         // 128 KiB
  u16* hb1   = (u16*)(ws + 172130304);         // 128 KiB
  int* cnt   = (int*)(ws + 172261376);         // 16 KiB

  float* outA = (float*)d_out;
  float* outh = outA + (long)M_*NACT;
  float* outc = outh + B_*H_;

  hipMemsetAsync(cnt, 0, T_*GR*sizeof(int), stream);
  k_cvt_obsT<<<M_*NOBS/8/256, 256, 0, stream>>>(obs, obsT);
  k_cvt<<<64, 256, 0, stream>>>(h0, hb0, B_*H_/4);
  k_transpose<<<2048, 256, 0, stream>>>(Wx, WxT, NOBS, G4);
  k_transpose<<<4096, 256, 0, stream>>>(Wh, WhT, H_, G4);
  k_transpose<<<1024, 256, 0, stream>>>(W1, W1T, H_, H_);
  k_transpose<<<1024, 256, 0, stream>>>(W2, W2T, H_, H_);
  k_transpose<<<64,   256, 0, stream>>>(Wo, WoT, H_, NACT);

  // persistent scan: 256 co-resident WGs (1/CU), fence-free island barriers
  k_scan<<<256, 256, 0, stream>>>(obsT, WxT, WhT, bb, c0, hb0, hb1, ys, outh, outc, cnt);

  // MLP head
  k_gemm_bt<1><<<(M_/128)*(H_/128), 256, 0, stream>>>(ys, W1T, t1, b1, M_, H_, H_);
  k_gemm_bt<1><<<(M_/128)*(H_/128), 256, 0, stream>>>(t1, W2T, t2, b2, M_, H_, H_);
  k_head<<<M_/64, 256, 0, stream>>>(t2, WoT, bo, amin, amax, outA);
}